// Round 13
// baseline (69.837 us; speedup 1.0000x reference)
//
#include <hip/hip_runtime.h>
#include <hip/hip_bf16.h>
#include <math.h>

#define B_ROWS 4096
#define NTOT   8192
#define DDIM   256
#define CSCALE 1.6986436f      // sqrt(2*log2(e)); zn scaled so A.B = 2*log2(e)*cos
#define NPART  8

typedef __attribute__((ext_vector_type(8))) short short8;   // 8 bf16
typedef __attribute__((ext_vector_type(4))) float f32x4;

static __device__ inline unsigned short f2bf(float x) {
    union { float f; unsigned u; } v; v.f = x;
    unsigned r = v.u + 0x7fffu + ((v.u >> 16) & 1u);  // RNE
    return (unsigned short)(r >> 16);
}

// ---- kernel 1: fused normalize (scaled bf16) + positive-pair sims + partials zeroing ----
__global__ __launch_bounds__(256) void norm_kernel(
        const float* __restrict__ zi, const float* __restrict__ zj,
        unsigned short* __restrict__ zn, float* __restrict__ simpos,
        float* __restrict__ parts) {
    int pair = blockIdx.x * 4 + (threadIdx.x >> 6);
    int lane = threadIdx.x & 63;
    float4 vi = reinterpret_cast<const float4*>(zi + (size_t)pair * DDIM)[lane];
    float4 vj = reinterpret_cast<const float4*>(zj + (size_t)pair * DDIM)[lane];
    float ssi = vi.x*vi.x + vi.y*vi.y + vi.z*vi.z + vi.w*vi.w;
    float ssj = vj.x*vj.x + vj.y*vj.y + vj.z*vj.z + vj.w*vj.w;
    float dij = vi.x*vj.x + vi.y*vj.y + vi.z*vj.z + vi.w*vj.w;
    #pragma unroll
    for (int o = 32; o > 0; o >>= 1) {
        ssi += __shfl_xor(ssi, o);
        ssj += __shfl_xor(ssj, o);
        dij += __shfl_xor(dij, o);
    }
    float invi = 1.0f / fmaxf(sqrtf(ssi), 1e-8f);
    float invj = 1.0f / fmaxf(sqrtf(ssj), 1e-8f);
    float si = CSCALE * invi, sj = CSCALE * invj;
    ushort4 hi4, hj4;
    hi4.x = f2bf(vi.x * si); hi4.y = f2bf(vi.y * si);
    hi4.z = f2bf(vi.z * si); hi4.w = f2bf(vi.w * si);
    hj4.x = f2bf(vj.x * sj); hj4.y = f2bf(vj.y * sj);
    hj4.z = f2bf(vj.z * sj); hj4.w = f2bf(vj.w * sj);
    *reinterpret_cast<ushort4*>(zn + (size_t)pair * DDIM + lane * 4) = hi4;
    *reinterpret_cast<ushort4*>(zn + (size_t)(pair + B_ROWS) * DDIM + lane * 4) = hj4;
    if (lane == 0) simpos[pair] = 2.0f * dij * invi * invj;   // logits = cos/tau
    if (blockIdx.x < 256) parts[blockIdx.x * 256 + threadIdx.x] = 0.0f;  // zero 64K floats
}

// ---- kernel 2 body: 128 rows x 128 cols, SINGLE full-tile stage (64 KB) ----
// 4 waves x 32 A-rows (a[2][8] = 64 VGPR). Stage all 128 cols once in two
// 8-load MLP bursts -> ONE barrier -> 8 subtiles of pure LDS compute with
// 4 independent depth-4 MFMA chains (k-half x rowset). 2 barriers/block total.
template<bool CROSS>
static __device__ __forceinline__ void sim_body(
        const unsigned short* __restrict__ zn, float* __restrict__ part,
        unsigned char* __restrict__ tile, float (* __restrict__ csum_lds)[128],
        int waveRow, int c0base) {
    int tid  = threadIdx.x;
    int wid  = tid >> 6;
    int lane = tid & 63;
    int l15  = lane & 15;
    int l4   = lane >> 4;

    // A fragments (16x16x32 layout: row = l15, k = m*32 + l4*8)
    short8 a[2][8];
    #pragma unroll
    for (int rs = 0; rs < 2; ++rs) {
        const unsigned short* ap = zn + (size_t)(waveRow + rs * 16 + l15) * DDIM;
        #pragma unroll
        for (int m = 0; m < 8; ++m)
            a[rs][m] = *reinterpret_cast<const short8*>(ap + m * 32 + l4 * 8);
    }

    // stage 128 cols x 512 B = 64 KB: 4096 x 16B chunks, 16/thread, two
    // 8-load bursts (32 VGPR live, brief). XOR swizzle ck^(tr&15) on LDS addr.
    #pragma unroll
    for (int g = 0; g < 2; ++g) {
        uint4 t[8];
        #pragma unroll
        for (int p = 0; p < 8; ++p) {
            int id = (g * 8 + p) * 256 + tid;
            int tr = id >> 5, ck = id & 31;
            t[p] = *reinterpret_cast<const uint4*>(
                zn + (size_t)(c0base + tr) * DDIM + ck * 8);
        }
        #pragma unroll
        for (int p = 0; p < 8; ++p) {
            int id = (g * 8 + p) * 256 + tid;
            int tr = id >> 5, ck = id & 31;
            *reinterpret_cast<uint4*>(tile + tr * 512 + ((ck ^ (tr & 15)) << 4)) = t[p];
        }
    }
    __syncthreads();

    float rsum[2][4] = {{0.f,0.f,0.f,0.f},{0.f,0.f,0.f,0.f}};

    #pragma unroll
    for (int sub = 0; sub < 8; ++sub) {
        const unsigned char* bbase = tile + (size_t)(sub * 16 + l15) * 512;
        // 4 independent MFMA chains: (rowset 0/1) x (k-half a/b), depth 4 each
        f32x4 acc0a = {0.f,0.f,0.f,0.f}, acc0b = {0.f,0.f,0.f,0.f};
        f32x4 acc1a = {0.f,0.f,0.f,0.f}, acc1b = {0.f,0.f,0.f,0.f};
        __builtin_amdgcn_s_setprio(1);
        #pragma unroll
        for (int m = 0; m < 4; ++m) {
            short8 bf0 = *reinterpret_cast<const short8*>(
                bbase + (((4 * m + l4) ^ l15) << 4));
            short8 bf1 = *reinterpret_cast<const short8*>(
                bbase + (((4 * (m + 4) + l4) ^ l15) << 4));
            acc0a = __builtin_amdgcn_mfma_f32_16x16x32_bf16(a[0][m],     bf0, acc0a, 0, 0, 0);
            acc1a = __builtin_amdgcn_mfma_f32_16x16x32_bf16(a[1][m],     bf0, acc1a, 0, 0, 0);
            acc0b = __builtin_amdgcn_mfma_f32_16x16x32_bf16(a[0][m + 4], bf1, acc0b, 0, 0, 0);
            acc1b = __builtin_amdgcn_mfma_f32_16x16x32_bf16(a[1][m + 4], bf1, acc1b, 0, 0, 0);
        }
        __builtin_amdgcn_s_setprio(0);
        int gcol = c0base + sub * 16 + l15;
        float cs = 0.0f;
        #pragma unroll
        for (int j = 0; j < 4; ++j) {
            float e0 = exp2f(acc0a[j] + acc0b[j]);   // zn pre-scaled: acc = 2*log2e*cos
            float e1 = exp2f(acc1a[j] + acc1b[j]);
            if (CROSS) {
                int g0 = waveRow + l4 * 4 + j;        // rowset 0
                e0 = (gcol > g0) ? e0 : 0.0f;
                e1 = (gcol > g0 + 16) ? e1 : 0.0f;    // rowset 1
            }
            rsum[0][j] += e0;
            rsum[1][j] += e1;
            cs += e0 + e1;
        }
        cs += __shfl_xor(cs, 16);
        cs += __shfl_xor(cs, 32);
        if (lane < 16) csum_lds[wid][sub * 16 + l15] = cs;
    }

    // ---- flush rows: reduce across the 16 col-lanes, one atomic per row ----
    #pragma unroll
    for (int rs = 0; rs < 2; ++rs)
        #pragma unroll
        for (int j = 0; j < 4; ++j) {
            float s = rsum[rs][j];
            #pragma unroll
            for (int m = 8; m >= 1; m >>= 1) s += __shfl_xor(s, m);
            if (l15 == 0)
                atomicAdd(&part[waveRow + rs * 16 + l4 * 4 + j], s);
        }

    // ---- flush cols: sum 4 waves' slices, one atomic per col ----
    __syncthreads();
    if (tid < 128) {
        float s = csum_lds[0][tid] + csum_lds[1][tid]
                + csum_lds[2][tid] + csum_lds[3][tid];
        atomicAdd(&part[c0base + tid], s);
    }
}

// 2080 uniform blocks: strip s (64 strips of 128 rows) has 64-s blocks of 128
// cols starting at the diagonal; prefix(s) = 64s - s(s-1)/2. rel==0 => CROSS.
// XCD-contiguous remap: 2080 = 8 x 260; dispatch round-robins XCDs, so
// blockIdx&7 == XCD; give each XCD a contiguous 260-unit range + its own
// part copy (all atomics XCD-local, staging reads XCD-L2-local).
__global__ __launch_bounds__(256, 2) void sim_kernel(
        const unsigned short* __restrict__ zn, float* __restrict__ parts) {
    __shared__ __align__(16) unsigned char tile[128 * 512];  // 64 KB
    __shared__ float csum_lds[4][128];                       // 2 KB

    int xcd = blockIdx.x & 7;
    int b   = xcd * 260 + (blockIdx.x >> 3);

    int s = (int)(64.5f - sqrtf(4160.25f - 2.0f * (float)b));
    if (s < 0) s = 0;
    if (s > 63) s = 63;
    while (s > 0 && b < 64 * s - (s * (s - 1)) / 2) --s;
    while (b >= 64 * (s + 1) - ((s + 1) * s) / 2) ++s;
    int rel = b - (64 * s - (s * (s - 1)) / 2);

    int waveRow = s * 128 + (threadIdx.x >> 6) * 32;
    int c0base  = (s + rel) * 128;
    float* part = parts + (size_t)xcd * NTOT;

    if (rel == 0) sim_body<true >(zn, part, tile, csum_lds, waveRow, c0base);
    else          sim_body<false>(zn, part, tile, csum_lds, waveRow, c0base);
}

// ---- kernel 3: loss = sum_r (log(sum_p parts[p][r]) - simpos[r % B]) / N ----
__global__ __launch_bounds__(1024) void finalize_kernel(
        const float* __restrict__ parts, const float* __restrict__ simpos,
        float* __restrict__ out) {
    __shared__ float red[16];
    int tid = threadIdx.x;
    float acc = 0.0f;
    #pragma unroll
    for (int rr = 0; rr < 8; ++rr) {
        int r = rr * 1024 + tid;
        float s = 0.0f;
        #pragma unroll
        for (int p = 0; p < NPART; ++p) s += parts[p * NTOT + r];
        acc += logf(s) - simpos[r & (B_ROWS - 1)];
    }
    #pragma unroll
    for (int o = 32; o > 0; o >>= 1) acc += __shfl_xor(acc, o);
    if ((tid & 63) == 0) red[tid >> 6] = acc;
    __syncthreads();
    if (tid == 0) {
        float t = 0.0f;
        #pragma unroll
        for (int w = 0; w < 16; ++w) t += red[w];
        out[0] = t / (float)NTOT;
    }
}

extern "C" void kernel_launch(void* const* d_in, const int* in_sizes, int n_in,
                              void* d_out, int out_size, void* d_ws, size_t ws_size,
                              hipStream_t stream) {
    const float* zi = (const float*)d_in[0];
    const float* zj = (const float*)d_in[1];
    float* out = (float*)d_out;

    unsigned short* zn = (unsigned short*)d_ws;                        // 4 MB
    float* parts  = (float*)((char*)d_ws + (size_t)NTOT * DDIM * 2);   // 256 KB
    float* simpos = parts + NPART * NTOT;                              // 16 KB

    norm_kernel<<<B_ROWS / 4, 256, 0, stream>>>(zi, zj, zn, simpos, parts);
    sim_kernel<<<2080, 256, 0, stream>>>(zn, parts);
    finalize_kernel<<<1, 1024, 0, stream>>>(parts, simpos, out);
}